// Round 10
// baseline (35.415 us; speedup 1.0000x reference)
//
#include <hip/hip_runtime.h>
#include <math.h>

static constexpr int B  = 4096;
static constexpr int L  = 4096;
static constexpr int NPART = 64;           // stats blocks; 64*256 = 16384 x-values
static constexpr int RPB = 2;              // rows per k_main block

typedef float f4 __attribute__((ext_vector_type(4)));

__device__ __constant__ float c_ps_powers[16] = {
    -5.0f, -4.0f, -3.0f, -2.0f, -1.5f, -1.0f, -0.5f, 0.0f,
     0.5f,  2.0f,  0.33333334f, 3.0f, 0.25f, 4.0f, 0.2f, 5.0f};

__device__ __constant__ float c_poly[5] = {2.0f, 5.0f, 8.0f, 11.0f, 14.0f};

// hardware transcendentals: v_log_f32 (log2 x), v_exp_f32 (2^x)
__device__ __forceinline__ float hw_log2(float x) { return __builtin_amdgcn_logf(x); }
__device__ __forceinline__ float hw_exp2(float x) { return __builtin_amdgcn_exp2f(x); }

// ---------------------------------------------------------------------------
// Kernel 1: 64 blocks x 256 threads — one x-value per thread.
// part[0..63] = block sums, part[64..127] = block sumsqs (f64).
// ---------------------------------------------------------------------------
__global__ __launch_bounds__(256)
void k_part(const float* __restrict__ pp, double* __restrict__ part) {
    const int tid = threadIdx.x;
    const int g   = blockIdx.x * 256 + tid;       // 0 .. 16383
    const float lx = hw_log2(pp[g]);
    float sf = 0.0f, sf2 = 0.0f;
    #pragma unroll
    for (int p = 0; p < 16; ++p) {
        const float t = hw_exp2(c_ps_powers[p] * lx);
        sf  += t;
        sf2 = fmaf(t, t, sf2);
    }
    __shared__ double sh_s[256];
    __shared__ double sh_s2[256];
    sh_s[tid]  = (double)sf;
    sh_s2[tid] = (double)sf2;
    __syncthreads();
    for (int off = 128; off > 0; off >>= 1) {
        if (tid < off) {
            sh_s[tid]  += sh_s[tid + off];
            sh_s2[tid] += sh_s2[tid + off];
        }
        __syncthreads();
    }
    if (tid == 0) {
        part[blockIdx.x]         = sh_s[0];
        part[NPART + blockIdx.x] = sh_s2[0];
    }
}

// ---------------------------------------------------------------------------
// Kernel 2: TWO rows per block, 512 threads.
//  - each thread's 4 eta float4 loads issued first (latency under prologue)
//  - prologue phases run on separate waves concurrently:
//      wave0+1: raw features for rows 0,1 ; wave2(lanes 0-63): stats reduce
//  - features + MLP -> 5 scaled coefficients per row in LDS
//  - batched compute + nontemporal store:
//      dy = c0'*e + c1'*e^4 + c2'*e^7 + c3'*e^10 + c4'*e^13  (ck' = ck*p_k)
// ---------------------------------------------------------------------------
__device__ __forceinline__ float poly_eval(float e, float c0, float c1,
                                           float c2, float c3, float c4) {
    const float e3 = e * e * e;
    float w   = e;             // e^1
    float acc = c0 * w;
    w *= e3;                   // e^4
    acc = fmaf(c1, w, acc);
    w *= e3;                   // e^7
    acc = fmaf(c2, w, acc);
    w *= e3;                   // e^10
    acc = fmaf(c3, w, acc);
    w *= e3;                   // e^13
    acc = fmaf(c4, w, acc);
    return acc;
}

__device__ __forceinline__ f4 poly_eval4(f4 e, float c0, float c1,
                                         float c2, float c3, float c4) {
    f4 r;
    r.x = poly_eval(e.x, c0, c1, c2, c3, c4);
    r.y = poly_eval(e.y, c0, c1, c2, c3, c4);
    r.z = poly_eval(e.z, c0, c1, c2, c3, c4);
    r.w = poly_eval(e.w, c0, c1, c2, c3, c4);
    return r;
}

__global__ __launch_bounds__(512)
void k_main(const float* __restrict__ pp,  const float* __restrict__ eta,
            const float* __restrict__ W1,  const float* __restrict__ b1,
            const float* __restrict__ W2,  const float* __restrict__ b2,
            const double* __restrict__ part, float* __restrict__ out) {
    const int tid  = threadIdx.x;
    const int row0 = blockIdx.x * RPB;
    const int rloc = tid >> 8;               // which of the 2 rows
    const int lt   = tid & 255;              // lane within the row's 256

    // ---- issue all global loads up front ----
    const f4* ep = reinterpret_cast<const f4*>(eta + (size_t)(row0 + rloc) * L);
    f4*       op = reinterpret_cast<f4*>(out + (size_t)(row0 + rloc) * L);
    const f4 e0 = ep[lt];
    const f4 e1 = ep[lt + 256];
    const f4 e2 = ep[lt + 512];
    const f4 e3 = ep[lt + 768];

    __shared__ float sh_r[RPB][64];   // features (raw t before normalize)
    __shared__ float sh_h[RPB][32];   // hidden layer
    __shared__ float sh_c[RPB][8];    // scaled coefficients
    __shared__ float sh_stat[2];      // mean, inv_std

    // ---- concurrent prologue: waves 0-1 features, wave 2 stats ----
    if (tid < 128) {
        const int r = tid >> 6;
        const int j = tid & 63;
        const float x = pp[(row0 + r) * 4 + (j >> 4)];
        sh_r[r][j] = hw_exp2(c_ps_powers[j & 15] * hw_log2(x));
    } else if (tid < 192) {
        const int l = tid - 128;
        double s  = part[l];
        double s2 = part[NPART + l];
        #pragma unroll
        for (int m = 32; m > 0; m >>= 1) {
            s  += __shfl_xor(s,  m, 64);
            s2 += __shfl_xor(s2, m, 64);
        }
        if (l == 0) {
            const double n    = 262144.0;
            const double mean = s / n;
            const double var  = (s2 - n * mean * mean) / (n - 1.0);
            sh_stat[0] = (float)mean;
            sh_stat[1] = (float)(1.0 / sqrt(var));
        }
    }
    __syncthreads();

    if (tid < 128) {
        const int r = tid >> 6;
        const int j = tid & 63;
        sh_r[r][j] = fmaxf((sh_r[r][j] - sh_stat[0]) * sh_stat[1], 0.0f);
    }
    __syncthreads();

    if (tid < 64) {                    // hidden: r = tid>>5, h = tid&31
        const int r = tid >> 5;
        const int h = tid & 31;
        float acc = b1[h];
        const float* w = W1 + h * 64;
        #pragma unroll
        for (int j = 0; j < 64; ++j) acc = fmaf(sh_r[r][j], w[j], acc);
        sh_h[r][h] = acc;
    }
    __syncthreads();

    if (tid < 16) {                    // out: r = tid>>3, k = tid&7
        const int r = tid >> 3;
        const int k = tid & 7;
        if (k < 5) {
            float acc = b2[k];
            const float* w = W2 + k * 32;
            #pragma unroll
            for (int o = 0; o < 32; ++o) acc = fmaf(sh_h[r][o], w[o], acc);
            sh_c[r][k] = acc * c_poly[k];
        }
    }
    __syncthreads();

    const float c0 = sh_c[rloc][0], c1 = sh_c[rloc][1], c2 = sh_c[rloc][2],
                c3 = sh_c[rloc][3], c4 = sh_c[rloc][4];

    // ---- batched compute + nontemporal store ----
    const f4 r0 = poly_eval4(e0, c0, c1, c2, c3, c4);
    const f4 r1 = poly_eval4(e1, c0, c1, c2, c3, c4);
    const f4 r2 = poly_eval4(e2, c0, c1, c2, c3, c4);
    const f4 r3 = poly_eval4(e3, c0, c1, c2, c3, c4);
    __builtin_nontemporal_store(r0, op + lt);
    __builtin_nontemporal_store(r1, op + lt + 256);
    __builtin_nontemporal_store(r2, op + lt + 512);
    __builtin_nontemporal_store(r3, op + lt + 768);
}

// ---------------------------------------------------------------------------
extern "C" void kernel_launch(void* const* d_in, const int* in_sizes, int n_in,
                              void* d_out, int out_size, void* d_ws, size_t ws_size,
                              hipStream_t stream) {
    const float* pp  = (const float*)d_in[0];   // [B,4]
    const float* eta = (const float*)d_in[1];   // [B,L]
    const float* W1  = (const float*)d_in[2];   // [32,64]
    const float* b1  = (const float*)d_in[3];   // [32]
    const float* W2  = (const float*)d_in[4];   // [5,32]
    const float* b2  = (const float*)d_in[5];   // [5]
    float* out   = (float*)d_out;
    double* part = (double*)d_ws;               // 2*NPART doubles (1 KB)

    k_part<<<NPART, 256, 0, stream>>>(pp, part);
    k_main<<<B / RPB, 512, 0, stream>>>(pp, eta, W1, b1, W2, b2, part, out);
}

// Round 11
// 33.612 us; speedup vs baseline: 1.0536x; 1.0536x over previous
//
#include <hip/hip_runtime.h>
#include <math.h>

static constexpr int B  = 4096;
static constexpr int L  = 4096;
static constexpr int NPART = 64;           // stats blocks; 64*256 = 16384 x-values

typedef float f4 __attribute__((ext_vector_type(4)));

__device__ __constant__ float c_ps_powers[16] = {
    -5.0f, -4.0f, -3.0f, -2.0f, -1.5f, -1.0f, -0.5f, 0.0f,
     0.5f,  2.0f,  0.33333334f, 3.0f, 0.25f, 4.0f, 0.2f, 5.0f};

__device__ __constant__ float c_poly[5] = {2.0f, 5.0f, 8.0f, 11.0f, 14.0f};

// hardware transcendentals: v_log_f32 (log2 x), v_exp_f32 (2^x)
__device__ __forceinline__ float hw_log2(float x) { return __builtin_amdgcn_logf(x); }
__device__ __forceinline__ float hw_exp2(float x) { return __builtin_amdgcn_exp2f(x); }

// ---------------------------------------------------------------------------
// Kernel 1: 64 blocks x 256 threads — one x-value per thread.
// part[0..63] = block sums, part[64..127] = block sumsqs (f64).
// ---------------------------------------------------------------------------
__global__ __launch_bounds__(256)
void k_part(const float* __restrict__ pp, double* __restrict__ part) {
    const int tid = threadIdx.x;
    const int g   = blockIdx.x * 256 + tid;       // 0 .. 16383
    const float lx = hw_log2(pp[g]);
    float sf = 0.0f, sf2 = 0.0f;
    #pragma unroll
    for (int p = 0; p < 16; ++p) {
        const float t = hw_exp2(c_ps_powers[p] * lx);
        sf  += t;
        sf2 = fmaf(t, t, sf2);
    }
    __shared__ double sh_s[256];
    __shared__ double sh_s2[256];
    sh_s[tid]  = (double)sf;
    sh_s2[tid] = (double)sf2;
    __syncthreads();
    for (int off = 128; off > 0; off >>= 1) {
        if (tid < off) {
            sh_s[tid]  += sh_s[tid + off];
            sh_s2[tid] += sh_s2[tid + off];
        }
        __syncthreads();
    }
    if (tid == 0) {
        part[blockIdx.x]         = sh_s[0];
        part[NPART + blockIdx.x] = sh_s2[0];
    }
}

// ---------------------------------------------------------------------------
// Kernel 2: one row per block.
//  - eta float4 loads issued first (latency hides under prologue; cached,
//    so eta stays L3-resident across replays)
//  - wave 1 reduces the 128 partials while wave 0 computes features
//  - features + MLP -> 5 scaled coefficients in LDS
//  - batched compute + NONTEMPORAL store (don't allocate out in L2/L3,
//    keeping eta resident):
//      dy = c0'*e + c1'*e^4 + c2'*e^7 + c3'*e^10 + c4'*e^13  (ck' = ck*p_k)
// ---------------------------------------------------------------------------
__device__ __forceinline__ float poly_eval(float e, float c0, float c1,
                                           float c2, float c3, float c4) {
    const float e3 = e * e * e;
    float w   = e;             // e^1
    float acc = c0 * w;
    w *= e3;                   // e^4
    acc = fmaf(c1, w, acc);
    w *= e3;                   // e^7
    acc = fmaf(c2, w, acc);
    w *= e3;                   // e^10
    acc = fmaf(c3, w, acc);
    w *= e3;                   // e^13
    acc = fmaf(c4, w, acc);
    return acc;
}

__device__ __forceinline__ f4 poly_eval4(f4 e, float c0, float c1,
                                         float c2, float c3, float c4) {
    f4 r;
    r.x = poly_eval(e.x, c0, c1, c2, c3, c4);
    r.y = poly_eval(e.y, c0, c1, c2, c3, c4);
    r.z = poly_eval(e.z, c0, c1, c2, c3, c4);
    r.w = poly_eval(e.w, c0, c1, c2, c3, c4);
    return r;
}

__global__ __launch_bounds__(256)
void k_main(const float* __restrict__ pp,  const float* __restrict__ eta,
            const float* __restrict__ W1,  const float* __restrict__ b1,
            const float* __restrict__ W2,  const float* __restrict__ b2,
            const double* __restrict__ part, float* __restrict__ out) {
    const int row = blockIdx.x;
    const int tid = threadIdx.x;

    // ---- issue all global loads up front ----
    const f4* ep = reinterpret_cast<const f4*>(eta + (size_t)row * L);
    f4*       op = reinterpret_cast<f4*>(out + (size_t)row * L);
    const f4 e0 = ep[tid];
    const f4 e1 = ep[tid + 256];
    const f4 e2 = ep[tid + 512];
    const f4 e3 = ep[tid + 768];

    __shared__ float sh_r[64];   // relu(norm) features (raw t before barrier)
    __shared__ float sh_h[32];   // hidden layer
    __shared__ float sh_c[8];    // scaled coefficients
    __shared__ float sh_stat[2]; // mean, inv_std

    // ---- wave 0: features (raw); wave 1: stats reduce — concurrent ----
    if (tid < 64) {
        const float x = pp[(row << 2) + (tid >> 4)];
        sh_r[tid] = hw_exp2(c_ps_powers[tid & 15] * hw_log2(x));
    } else if (tid < 128) {
        const int l = tid - 64;
        double s  = part[l];
        double s2 = part[NPART + l];
        #pragma unroll
        for (int m = 32; m > 0; m >>= 1) {
            s  += __shfl_xor(s,  m, 64);
            s2 += __shfl_xor(s2, m, 64);
        }
        if (l == 0) {
            const double n    = 262144.0;
            const double mean = s / n;
            const double var  = (s2 - n * mean * mean) / (n - 1.0);
            sh_stat[0] = (float)mean;
            sh_stat[1] = (float)(1.0 / sqrt(var));
        }
    }
    __syncthreads();

    if (tid < 64) {
        sh_r[tid] = fmaxf((sh_r[tid] - sh_stat[0]) * sh_stat[1], 0.0f);
    }
    __syncthreads();

    if (tid < 32) {
        float acc = b1[tid];
        const float* w = W1 + tid * 64;
        #pragma unroll
        for (int j = 0; j < 64; ++j) acc = fmaf(sh_r[j], w[j], acc);
        sh_h[tid] = acc;
    }
    __syncthreads();

    if (tid < 5) {
        float acc = b2[tid];
        const float* w = W2 + tid * 32;
        #pragma unroll
        for (int o = 0; o < 32; ++o) acc = fmaf(sh_h[o], w[o], acc);
        sh_c[tid] = acc * c_poly[tid];
    }
    __syncthreads();

    const float c0 = sh_c[0], c1 = sh_c[1], c2 = sh_c[2],
                c3 = sh_c[3], c4 = sh_c[4];

    // ---- batched compute + nontemporal store ----
    const f4 r0 = poly_eval4(e0, c0, c1, c2, c3, c4);
    const f4 r1 = poly_eval4(e1, c0, c1, c2, c3, c4);
    const f4 r2 = poly_eval4(e2, c0, c1, c2, c3, c4);
    const f4 r3 = poly_eval4(e3, c0, c1, c2, c3, c4);
    __builtin_nontemporal_store(r0, op + tid);
    __builtin_nontemporal_store(r1, op + tid + 256);
    __builtin_nontemporal_store(r2, op + tid + 512);
    __builtin_nontemporal_store(r3, op + tid + 768);
}

// ---------------------------------------------------------------------------
extern "C" void kernel_launch(void* const* d_in, const int* in_sizes, int n_in,
                              void* d_out, int out_size, void* d_ws, size_t ws_size,
                              hipStream_t stream) {
    const float* pp  = (const float*)d_in[0];   // [B,4]
    const float* eta = (const float*)d_in[1];   // [B,L]
    const float* W1  = (const float*)d_in[2];   // [32,64]
    const float* b1  = (const float*)d_in[3];   // [32]
    const float* W2  = (const float*)d_in[4];   // [5,32]
    const float* b2  = (const float*)d_in[5];   // [5]
    float* out   = (float*)d_out;
    double* part = (double*)d_ws;               // 2*NPART doubles (1 KB)

    k_part<<<NPART, 256, 0, stream>>>(pp, part);
    k_main<<<B, 256, 0, stream>>>(pp, eta, W1, b1, W2, b2, part, out);
}